// Round 15
// baseline (258.092 us; speedup 1.0000x reference)
//
#include <hip/hip_runtime.h>
#include <math.h>

#define B_ 4
#define S_ 2048
#define D_ 1024
#define H_ 16
#define HD_ 64
#define M_ (B_*S_)     // 8192
#define BH_ (B_*H_)    // 64

typedef __attribute__((ext_vector_type(4))) float f32x4;
typedef _Float16 f16;
typedef __attribute__((ext_vector_type(8))) _Float16 f16x8;
typedef __attribute__((ext_vector_type(2))) __fp16 fp16x2_raw;   // builtin return type
typedef unsigned short u16;

// Q pre-scale: (1/8) * log2(e) so attention P = exp2(score)
#define QSCALE 0.18033688011112042f

// ---------------- helpers ----------------
// packed f32x2 -> f16x2 (v_cvt_pkrtz_f16_f32)
__device__ __forceinline__ unsigned pkh(float a, float b) {
    fp16x2_raw h = __builtin_amdgcn_cvt_pkrtz(a, b);
    unsigned r; __builtin_memcpy(&r, &h, 4);
    return r;
}
__device__ __forceinline__ uint2 f4_to_h4(float4 v) {
    uint2 r;
    r.x = pkh(v.x, v.y);
    r.y = pkh(v.z, v.w);
    return r;
}
__device__ __forceinline__ void gload_lds16(const void* g, void* l) {
    __builtin_amdgcn_global_load_lds(
        (const __attribute__((address_space(1))) void*)g,
        (__attribute__((address_space(3))) void*)l, 16, 0, 0);
}
#define MFMA16(a,b,c) __builtin_amdgcn_mfma_f32_16x16x32_f16((a),(b),(c),0,0,0)

// ---------------- W converter: 4 segments of 1M floats -> f16 ----------------
__global__ __launch_bounds__(256) void conv_w_kernel(
    const float* __restrict__ w0, const float* __restrict__ w1,
    const float* __restrict__ w2, const float* __restrict__ w3,
    f16* __restrict__ out)
{
    const float* src = (blockIdx.y==0)?w0:(blockIdx.y==1)?w1:(blockIdx.y==2)?w2:w3;
    size_t off = (size_t)blockIdx.y << 20;
    size_t i = ((size_t)blockIdx.x*256 + threadIdx.x)*4;
    float4 v = *(const float4*)&src[i];
    *(uint2*)&out[off + i] = f4_to_h4(v);
}

// ---------------- input converter: 8.39M floats -> f16 ----------------
__global__ __launch_bounds__(256) void conv_in_kernel(
    const float* __restrict__ src, f16* __restrict__ out)
{
    size_t i = ((size_t)blockIdx.x*256 + threadIdx.x)*4;
    float4 v = *(const float4*)&src[i];
    *(uint2*)&out[i] = f4_to_h4(v);
}

// ---------------------------------------------------------------------------
// Pure-f16 m97-structure GEMM: C(m,n) = sum_k A[m,k]*W[n,k] + bias[n]
// Per K-step: 4 global_load_lds (A:2, B:2) + 8 ds_read_b128 + 16 MFMA.
// MODE 0: out = q f16 [bh][s][64], scaled QSCALE
// MODE 1: out = k f16 [bh][s][64]
// MODE 2: out = v^T f16 [bh][hd][s]
// MODE 3: A gathered from f16 [bh][s][64] (per-lane gload src); out fp32 [m][1024]
// ---------------------------------------------------------------------------
template<int MODE>
__global__ __launch_bounds__(256, 2) void gemm_mfma(
    const f16* __restrict__ Af16,
    const f16* __restrict__ Wh16,
    const float* __restrict__ bias,
    void* out0)
{
    __shared__ u16 Ah[128][32];   // 8KB (f16 storage)
    __shared__ u16 Bh[128][32];   // 8KB

    const int t = threadIdx.x;
    const int lane = t & 63;
    const int w = t >> 6;
    const int wm = w >> 1, wn = w & 1;
    const int m0 = (int)(blockIdx.x >> 3) * 128;
    const int n0 = (int)(blockIdx.x & 7) * 128;

    const int srow_base = w*32;            // + c*16
    const int lrow_off  = lane >> 2;       // 0..15
    const int k8        = (lane & 3) * 8;  // 0,8,16,24

    f32x4 acc[4][4];
    #pragma unroll
    for (int i = 0; i < 4; ++i)
        #pragma unroll
        for (int j = 0; j < 4; ++j) { f32x4 z = {0.f,0.f,0.f,0.f}; acc[i][j] = z; }

    for (int k0 = 0; k0 < D_; k0 += 32) {
        __syncthreads();   // B0: prior ds_reads complete
        #pragma unroll
        for (int c = 0; c < 2; ++c) {
            int lrow = srow_base + c*16;
            int row = lrow + lrow_off;
            int kw = k8 ^ ((row & 3) << 3);
            size_t asrc;
            if constexpr (MODE == 3) {
                int m = m0 + row;
                int b = m >> 11, s = m & 2047;
                int kk = k0 + kw;
                asrc = (((size_t)b*H_ + (kk >> 6))*S_ + s)*HD_ + (kk & 63);
            } else {
                asrc = (size_t)(m0 + row)*D_ + k0 + kw;
            }
            gload_lds16(&Af16[asrc], &Ah[lrow][0]);
            gload_lds16(&Wh16[(size_t)(n0 + row)*D_ + k0 + kw], &Bh[lrow][0]);
        }
        __syncthreads();   // B1: staged (vmcnt drained)

        f16x8 ah[4], bh4[4];
        #pragma unroll
        for (int i = 0; i < 4; ++i) {
            int ml = wm*64 + i*16 + (lane & 15);
            int kwa = ((lane >> 4) * 8) ^ ((ml & 3) << 3);
            ah[i] = *(const f16x8*)&Ah[ml][kwa];
            int nl = wn*64 + i*16 + (lane & 15);
            int kwb = ((lane >> 4) * 8) ^ ((nl & 3) << 3);
            bh4[i] = *(const f16x8*)&Bh[nl][kwb];
        }
        __builtin_amdgcn_s_setprio(1);
        #pragma unroll
        for (int i = 0; i < 4; ++i)
            #pragma unroll
            for (int j = 0; j < 4; ++j)
                acc[i][j] = MFMA16(ah[i], bh4[j], acc[i][j]);
        __builtin_amdgcn_s_setprio(0);
    }

    // epilogue
    #pragma unroll
    for (int i = 0; i < 4; ++i) {
        #pragma unroll
        for (int j = 0; j < 4; ++j) {
            int n = n0 + wn*64 + j*16 + (lane & 15);
            float bb = bias[n];
            int mbase = m0 + wm*64 + i*16 + (lane >> 4)*4;
            if constexpr (MODE == 3) {
                float* o = (float*)out0;
                #pragma unroll
                for (int r = 0; r < 4; ++r)
                    o[(size_t)(mbase + r)*D_ + n] = acc[i][j][r] + bb;
            } else if constexpr (MODE == 0) {
                f16* q = (f16*)out0;
                int b = mbase >> 11, h = n >> 6, hd = n & 63;
                size_t bh = (size_t)b*H_ + h;
                #pragma unroll
                for (int r = 0; r < 4; ++r) {
                    int s = (mbase + r) & 2047;
                    q[(bh*S_ + s)*64 + hd] = (f16)((acc[i][j][r] + bb) * QSCALE);
                }
            } else if constexpr (MODE == 1) {
                f16* oh = (f16*)out0;
                int b = mbase >> 11, h = n >> 6, hd = n & 63;
                size_t bh = (size_t)b*H_ + h;
                #pragma unroll
                for (int r = 0; r < 4; ++r) {
                    int s = (mbase + r) & 2047;
                    oh[(bh*S_ + s)*64 + hd] = (f16)(acc[i][j][r] + bb);
                }
            } else { // MODE 2: transposed V
                int b = mbase >> 11, h = n >> 6, hd = n & 63;
                int s0 = mbase & 2047;
                uint2 ph;
                ph.x = pkh(acc[i][j][0] + bb, acc[i][j][1] + bb);
                ph.y = pkh(acc[i][j][2] + bb, acc[i][j][3] + bb);
                size_t idx = (((size_t)b*H_ + h)*HD_ + hd)*S_ + s0;
                *(uint2*)&((f16*)out0)[idx] = ph;
            }
        }
    }
}

// ---------------------------------------------------------------------------
// MFMA flash attention v8: double-buffered K/V + counted vmcnt (m201 T3/T4).
// QBLK=256 as 4 waves x 64 q-rows.
// Per kt: issue next tile's 4 gload_lds -> s_waitcnt vmcnt(4) (current tile
// done, next stays in flight) -> raw s_barrier -> compute -> raw s_barrier.
// NO full vmcnt(0) drain in the main loop: load latency hides under compute.
// Safety: every ds_read is consumed by an MFMA in-iteration (lgkmcnt dep
// before barrier); end barrier protects buf[cur] before kt+1 restages it;
// Ps is wave-private (no barrier).
// LDS 64KB -> 2 blocks/CU (grid 512 = 2/CU). (256,2): VGPR cap 256.
// ---------------------------------------------------------------------------
__global__ __launch_bounds__(256, 2) void attn_mfma(
    const f16* __restrict__ kf,                        // [bh][s][64]
    const f16* __restrict__ vtf,                       // [bh][hd][s]
    f16* qf)                                           // [bh][s][64] in/out
{
    __shared__ u16 Kh[2][64][64];    // 16KB (f16 storage)
    __shared__ u16 Vth[2][64][64];   // 16KB  [hd][kv]
    __shared__ u16 Ps[256][64];      // 32KB (wave-private rows)

    const int t = threadIdx.x;
    const int lane = t & 63;
    const int w = t >> 6;            // 0..3
    const int g = lane >> 4;         // 0..3
    const int l15 = lane & 15;

    // bijective XCD swizzle: hw block -> logical (bh, qtile)
    const int lb = (int)blockIdx.x;
    const int logical = (lb & 7) * 64 + (lb >> 3);   // grid 512 = 8*64
    const int qtile = logical & 7;                   // 8 q-tiles of 256 rows
    const int bh = logical >> 3;
    const size_t rowb = (size_t)bh * S_;
    const int q0 = qtile * 256;

    // staging coords (uniform LDS row base per wave; per-lane global src)
    const int srow_off = lane >> 3;          // 0..7
    const int sd8      = (lane & 7) * 8;

    // Q fragments: 64 rows per wave (pre-scaled by QSCALE at projection)
    f16x8 qh[4][2];
    {
        int qr = q0 + w*64 + l15;
        #pragma unroll
        for (int mi = 0; mi < 4; ++mi)
            #pragma unroll
            for (int kk = 0; kk < 2; ++kk) {
                int d0 = kk*32 + g*8;
                qh[mi][kk] = *(const f16x8*)&qf[(rowb + qr + mi*16)*64 + d0];
            }
    }

    f32x4 O[4][4];
    float lsum[4] = {0.f, 0.f, 0.f, 0.f};
    #pragma unroll
    for (int mi = 0; mi < 4; ++mi)
        #pragma unroll
        for (int oj = 0; oj < 4; ++oj) { f32x4 z = {0.f,0.f,0.f,0.f}; O[mi][oj] = z; }

#define STAGE_KV(bsel, kt_) do { \
        _Pragma("unroll") \
        for (int c = 0; c < 2; ++c) { \
            int lrow = w*16 + c*8; \
            int row = lrow + srow_off; \
            int dsw = sd8 ^ ((row & 7) << 3); \
            size_t kg = (rowb + (kt_)*64 + row)*64 + dsw; \
            size_t vg = ((size_t)bh*HD_ + row)*S_ + (kt_)*64 + dsw; \
            gload_lds16(&kf[kg],  &Kh[bsel][lrow][0]); \
            gload_lds16(&vtf[vg], &Vth[bsel][lrow][0]); \
        } \
    } while (0)

    // prologue: stage tile 0 into buf 0
    STAGE_KV(0, 0);

    const int NT = S_/64;   // 32
    for (int kt = 0; kt < NT; ++kt) {
        const int cur = kt & 1;
        if (kt + 1 < NT) {
            STAGE_KV(cur ^ 1, kt + 1);                    // next tile in flight
            asm volatile("s_waitcnt vmcnt(4)" ::: "memory");  // cur tile landed
        } else {
            asm volatile("s_waitcnt vmcnt(0)" ::: "memory");
        }
        __builtin_amdgcn_s_barrier();   // all waves' cur-tile loads complete

        // ---- S^T = (K Q^T) single-term f16, sa[kvblock][qblock] ----
        f32x4 sa[4][4];
        #pragma unroll
        for (int k4 = 0; k4 < 4; ++k4)
            #pragma unroll
            for (int qt = 0; qt < 4; ++qt) { f32x4 z = {0.f,0.f,0.f,0.f}; sa[k4][qt] = z; }
        #pragma unroll
        for (int kk = 0; kk < 2; ++kk) {
            f16x8 kb[4];
            #pragma unroll
            for (int k4 = 0; k4 < 4; ++k4) {
                int kv = k4*16 + l15;
                int dw = (kk*32 + g*8) ^ ((kv & 7) << 3);
                kb[k4] = *(const f16x8*)&Kh[cur][kv][dw];
            }
            __builtin_amdgcn_s_setprio(1);
            #pragma unroll
            for (int k4 = 0; k4 < 4; ++k4)
                #pragma unroll
                for (int qt = 0; qt < 4; ++qt)
                    sa[k4][qt] = MFMA16(kb[k4], qh[qt][kk], sa[k4][qt]);
            __builtin_amdgcn_s_setprio(0);
        }

        // ---- P = exp2(score); per-lane unrounded l; packed b64 P writes ----
        u16* Pflat = &Ps[0][0];
        #pragma unroll
        for (int qt = 0; qt < 4; ++qt) {
            int qw = w*64 + qt*16 + l15;
            int prow = qw * 64;
            int sw = (qw & 7) << 3;
            #pragma unroll
            for (int k4 = 0; k4 < 4; ++k4) {
                float p0 = exp2f(sa[k4][qt][0]);
                float p1 = exp2f(sa[k4][qt][1]);
                float p2 = exp2f(sa[k4][qt][2]);
                float p3 = exp2f(sa[k4][qt][3]);
                lsum[qt] += (p0 + p1) + (p2 + p3);
                uint2 pk;
                pk.x = pkh(p0, p1);
                pk.y = pkh(p2, p3);
                int kvb = k4*16 + g*4;
                *(uint2*)&Pflat[prow + (kvb ^ sw)] = pk;
            }
        }
        // no barrier: P rows are wave-private (written and read by same wave)

        // ---- PV (f16 single-term) ----
        #pragma unroll
        for (int k2 = 0; k2 < 2; ++k2) {
            f16x8 pa[4], vb[4];
            #pragma unroll
            for (int mi = 0; mi < 4; ++mi) {
                int q = w*64 + mi*16 + l15;
                int kw = (k2*32 + g*8) ^ ((q & 7) << 3);
                pa[mi] = *(const f16x8*)&Pflat[q*64 + kw];
            }
            #pragma unroll
            for (int oj = 0; oj < 4; ++oj) {
                int hd = oj*16 + l15;
                int kw = (k2*32 + g*8) ^ ((hd & 7) << 3);
                vb[oj] = *(const f16x8*)&Vth[cur][hd][kw];
            }
            __builtin_amdgcn_s_setprio(1);
            #pragma unroll
            for (int mi = 0; mi < 4; ++mi)
                #pragma unroll
                for (int oj = 0; oj < 4; ++oj)
                    O[mi][oj] = MFMA16(pa[mi], vb[oj], O[mi][oj]);
            __builtin_amdgcn_s_setprio(0);
        }

        __builtin_amdgcn_s_barrier();   // buf[cur] reads done before restage
    }
#undef STAGE_KV

    // ---- final l reduce (q-class lanes: l15, +16, +32, +48) ----
    float inv[4];
    #pragma unroll
    for (int qt = 0; qt < 4; ++qt) {
        float l = lsum[qt];
        l += __shfl_xor(l, 16, 64);
        l += __shfl_xor(l, 32, 64);
        inv[qt] = 1.f / l;
    }
    // ---- normalize + store f16 in-place over own qf rows ----
    #pragma unroll
    for (int mi = 0; mi < 4; ++mi)
        #pragma unroll
        for (int r = 0; r < 4; ++r) {
            float iv = __shfl(inv[mi], g*4 + r, 64);
            int q = q0 + w*64 + mi*16 + g*4 + r;
            #pragma unroll
            for (int oj = 0; oj < 4; ++oj) {
                int hd = oj*16 + l15;
                qf[(rowb + q)*HD_ + hd] = (f16)(O[mi][oj][r] * iv);
            }
        }
}

extern "C" void kernel_launch(void* const* d_in, const int* in_sizes, int n_in,
                              void* d_out, int out_size, void* d_ws, size_t ws_size,
                              hipStream_t stream) {
    const float* query = (const float*)d_in[0];
    const float* key_  = (const float*)d_in[1];
    const float* value = (const float*)d_in[2];
    const float* Wq    = (const float*)d_in[3];
    const float* bq    = (const float*)d_in[4];
    const float* Wk    = (const float*)d_in[5];
    const float* bk    = (const float*)d_in[6];
    const float* Wv    = (const float*)d_in[7];
    const float* bv    = (const float*)d_in[8];
    const float* Wo    = (const float*)d_in[9];
    const float* bo    = (const float*)d_in[10];
    float* out = (float*)d_out;

    char* wsb = (char*)d_ws;
    const size_t SZ_H = (size_t)BH_*S_*64*2;          // 16.78 MB per f16 tensor
    f16* qf   = (f16*)wsb;                            // q -> attn O (in-place)
    f16* kf   = (f16*)(wsb + SZ_H);
    f16* vtf  = (f16*)(wsb + 2*SZ_H);
    f16* in16 = (f16*)(wsb + 3*SZ_H);                 // reused per input
    f16* W16  = (f16*)(wsb + 4*SZ_H);                 // [4][1<<20] f16 = 8 MB
    // total: 4*16.78 + 8 = 75.1 MB (< 100.7 MB proven available in r1)

    dim3 gGemm(512);    // (8192/128)*(1024/128)
    dim3 gAttn(512);    // 64 bh * 8 q-tiles of 256
    dim3 gConv(8192);   // 8.39M/4/256

    conv_w_kernel<<<dim3(1024,4), 256, 0, stream>>>(Wq, Wk, Wv, Wo, W16);
    conv_in_kernel<<<gConv, 256, 0, stream>>>(query, in16);
    gemm_mfma<0><<<gGemm, 256, 0, stream>>>(in16, W16 + ((size_t)0<<20), bq, qf);
    conv_in_kernel<<<gConv, 256, 0, stream>>>(key_, in16);
    gemm_mfma<1><<<gGemm, 256, 0, stream>>>(in16, W16 + ((size_t)1<<20), bk, kf);
    conv_in_kernel<<<gConv, 256, 0, stream>>>(value, in16);
    gemm_mfma<2><<<gGemm, 256, 0, stream>>>(in16, W16 + ((size_t)2<<20), bv, vtf);
    attn_mfma<<<gAttn, 256, 0, stream>>>(kf, vtf, qf);
    gemm_mfma<3><<<gGemm, 256, 0, stream>>>(qf, W16 + ((size_t)3<<20), bo, out);
}

// Round 16
// 248.783 us; speedup vs baseline: 1.0374x; 1.0374x over previous
//
#include <hip/hip_runtime.h>
#include <math.h>

#define B_ 4
#define S_ 2048
#define D_ 1024
#define H_ 16
#define HD_ 64
#define M_ (B_*S_)     // 8192
#define BH_ (B_*H_)    // 64

typedef __attribute__((ext_vector_type(4))) float f32x4;
typedef _Float16 f16;
typedef __attribute__((ext_vector_type(8))) _Float16 f16x8;
typedef __attribute__((ext_vector_type(2))) __fp16 fp16x2_raw;   // builtin return type
typedef unsigned short u16;

// Q pre-scale: (1/8) * log2(e) so attention P = exp2(score)
#define QSCALE 0.18033688011112042f

// ---------------- helpers ----------------
// packed f32x2 -> f16x2 (v_cvt_pkrtz_f16_f32)
__device__ __forceinline__ unsigned pkh(float a, float b) {
    fp16x2_raw h = __builtin_amdgcn_cvt_pkrtz(a, b);
    unsigned r; __builtin_memcpy(&r, &h, 4);
    return r;
}
__device__ __forceinline__ uint2 f4_to_h4(float4 v) {
    uint2 r;
    r.x = pkh(v.x, v.y);
    r.y = pkh(v.z, v.w);
    return r;
}
__device__ __forceinline__ void gload_lds16(const void* g, void* l) {
    __builtin_amdgcn_global_load_lds(
        (const __attribute__((address_space(1))) void*)g,
        (__attribute__((address_space(3))) void*)l, 16, 0, 0);
}
#define MFMA16(a,b,c) __builtin_amdgcn_mfma_f32_16x16x32_f16((a),(b),(c),0,0,0)

// ---------------- W converter: 4 segments of 1M floats -> f16 ----------------
__global__ __launch_bounds__(256) void conv_w_kernel(
    const float* __restrict__ w0, const float* __restrict__ w1,
    const float* __restrict__ w2, const float* __restrict__ w3,
    f16* __restrict__ out)
{
    const float* src = (blockIdx.y==0)?w0:(blockIdx.y==1)?w1:(blockIdx.y==2)?w2:w3;
    size_t off = (size_t)blockIdx.y << 20;
    size_t i = ((size_t)blockIdx.x*256 + threadIdx.x)*4;
    float4 v = *(const float4*)&src[i];
    *(uint2*)&out[off + i] = f4_to_h4(v);
}

// ---------------- input converter: 8.39M floats -> f16 ----------------
__global__ __launch_bounds__(256) void conv_in_kernel(
    const float* __restrict__ src, f16* __restrict__ out)
{
    size_t i = ((size_t)blockIdx.x*256 + threadIdx.x)*4;
    float4 v = *(const float4*)&src[i];
    *(uint2*)&out[i] = f4_to_h4(v);
}

// ---------------------------------------------------------------------------
// Pure-f16 m97-structure GEMM: C(m,n) = sum_k A[m,k]*W[n,k] + bias[n]
// Per K-step: 4 global_load_lds (A:2, B:2) + 8 ds_read_b128 + 16 MFMA.
// MODE 0: out = q f16 [bh][s][64], scaled QSCALE
// MODE 1: out = k f16 [bh][s][64]
// MODE 2: out = v^T f16 [bh][hd][s]
// MODE 3: A gathered from f16 [bh][s][64] (per-lane gload src); out fp32 [m][1024]
// ---------------------------------------------------------------------------
template<int MODE>
__global__ __launch_bounds__(256, 2) void gemm_mfma(
    const f16* __restrict__ Af16,
    const f16* __restrict__ Wh16,
    const float* __restrict__ bias,
    void* out0)
{
    __shared__ u16 Ah[128][32];   // 8KB (f16 storage)
    __shared__ u16 Bh[128][32];   // 8KB

    const int t = threadIdx.x;
    const int lane = t & 63;
    const int w = t >> 6;
    const int wm = w >> 1, wn = w & 1;
    const int m0 = (int)(blockIdx.x >> 3) * 128;
    const int n0 = (int)(blockIdx.x & 7) * 128;

    const int srow_base = w*32;            // + c*16
    const int lrow_off  = lane >> 2;       // 0..15
    const int k8        = (lane & 3) * 8;  // 0,8,16,24

    f32x4 acc[4][4];
    #pragma unroll
    for (int i = 0; i < 4; ++i)
        #pragma unroll
        for (int j = 0; j < 4; ++j) { f32x4 z = {0.f,0.f,0.f,0.f}; acc[i][j] = z; }

    for (int k0 = 0; k0 < D_; k0 += 32) {
        __syncthreads();   // B0: prior ds_reads complete
        #pragma unroll
        for (int c = 0; c < 2; ++c) {
            int lrow = srow_base + c*16;
            int row = lrow + lrow_off;
            int kw = k8 ^ ((row & 3) << 3);
            size_t asrc;
            if constexpr (MODE == 3) {
                int m = m0 + row;
                int b = m >> 11, s = m & 2047;
                int kk = k0 + kw;
                asrc = (((size_t)b*H_ + (kk >> 6))*S_ + s)*HD_ + (kk & 63);
            } else {
                asrc = (size_t)(m0 + row)*D_ + k0 + kw;
            }
            gload_lds16(&Af16[asrc], &Ah[lrow][0]);
            gload_lds16(&Wh16[(size_t)(n0 + row)*D_ + k0 + kw], &Bh[lrow][0]);
        }
        __syncthreads();   // B1: staged (vmcnt drained)

        f16x8 ah[4], bh4[4];
        #pragma unroll
        for (int i = 0; i < 4; ++i) {
            int ml = wm*64 + i*16 + (lane & 15);
            int kwa = ((lane >> 4) * 8) ^ ((ml & 3) << 3);
            ah[i] = *(const f16x8*)&Ah[ml][kwa];
            int nl = wn*64 + i*16 + (lane & 15);
            int kwb = ((lane >> 4) * 8) ^ ((nl & 3) << 3);
            bh4[i] = *(const f16x8*)&Bh[nl][kwb];
        }
        __builtin_amdgcn_s_setprio(1);
        #pragma unroll
        for (int i = 0; i < 4; ++i)
            #pragma unroll
            for (int j = 0; j < 4; ++j)
                acc[i][j] = MFMA16(ah[i], bh4[j], acc[i][j]);
        __builtin_amdgcn_s_setprio(0);
    }

    // epilogue
    #pragma unroll
    for (int i = 0; i < 4; ++i) {
        #pragma unroll
        for (int j = 0; j < 4; ++j) {
            int n = n0 + wn*64 + j*16 + (lane & 15);
            float bb = bias[n];
            int mbase = m0 + wm*64 + i*16 + (lane >> 4)*4;
            if constexpr (MODE == 3) {
                float* o = (float*)out0;
                #pragma unroll
                for (int r = 0; r < 4; ++r)
                    o[(size_t)(mbase + r)*D_ + n] = acc[i][j][r] + bb;
            } else if constexpr (MODE == 0) {
                f16* q = (f16*)out0;
                int b = mbase >> 11, h = n >> 6, hd = n & 63;
                size_t bh = (size_t)b*H_ + h;
                #pragma unroll
                for (int r = 0; r < 4; ++r) {
                    int s = (mbase + r) & 2047;
                    q[(bh*S_ + s)*64 + hd] = (f16)((acc[i][j][r] + bb) * QSCALE);
                }
            } else if constexpr (MODE == 1) {
                f16* oh = (f16*)out0;
                int b = mbase >> 11, h = n >> 6, hd = n & 63;
                size_t bh = (size_t)b*H_ + h;
                #pragma unroll
                for (int r = 0; r < 4; ++r) {
                    int s = (mbase + r) & 2047;
                    oh[(bh*S_ + s)*64 + hd] = (f16)(acc[i][j][r] + bb);
                }
            } else { // MODE 2: transposed V
                int b = mbase >> 11, h = n >> 6, hd = n & 63;
                int s0 = mbase & 2047;
                uint2 ph;
                ph.x = pkh(acc[i][j][0] + bb, acc[i][j][1] + bb);
                ph.y = pkh(acc[i][j][2] + bb, acc[i][j][3] + bb);
                size_t idx = (((size_t)b*H_ + h)*HD_ + hd)*S_ + s0;
                *(uint2*)&((f16*)out0)[idx] = ph;
            }
        }
    }
}

// ---------------------------------------------------------------------------
// MFMA flash attention v9: VALU diet (r15 showed VALU-issue-bound, 58% busy).
// r16: (a) l-sum via MFMA against an all-ones B fragment (P·1 row-sum) —
//   kills 64 VALU adds/kt AND the final cross-lane reduce (lacc[mi][r]
//   aligns with O rows); (b) sa zero-init via shared zero4 C-input on the
//   first QK^T k-slice — kills 64 v_mov/kt. Remaining VALU/kt ~= 64 exp2
//   + 32 cvt_pk (irreducible).
// QBLK=256 as 4 waves x 64 q-rows; dbuf K/V + counted vmcnt (r15, neutral
// but verified); no-max softmax; XCD swizzle; setprio on MFMA clusters.
// LDS 64KB -> 2 blocks/CU (grid 512 = 2/CU). (256,2): VGPR cap 256.
// ---------------------------------------------------------------------------
__global__ __launch_bounds__(256, 2) void attn_mfma(
    const f16* __restrict__ kf,                        // [bh][s][64]
    const f16* __restrict__ vtf,                       // [bh][hd][s]
    f16* qf)                                           // [bh][s][64] in/out
{
    __shared__ u16 Kh[2][64][64];    // 16KB (f16 storage)
    __shared__ u16 Vth[2][64][64];   // 16KB  [hd][kv]
    __shared__ u16 Ps[256][64];      // 32KB (wave-private rows)

    const int t = threadIdx.x;
    const int lane = t & 63;
    const int w = t >> 6;            // 0..3
    const int g = lane >> 4;         // 0..3
    const int l15 = lane & 15;

    // bijective XCD swizzle: hw block -> logical (bh, qtile)
    const int lb = (int)blockIdx.x;
    const int logical = (lb & 7) * 64 + (lb >> 3);   // grid 512 = 8*64
    const int qtile = logical & 7;                   // 8 q-tiles of 256 rows
    const int bh = logical >> 3;
    const size_t rowb = (size_t)bh * S_;
    const int q0 = qtile * 256;

    // staging coords (uniform LDS row base per wave; per-lane global src)
    const int srow_off = lane >> 3;          // 0..7
    const int sd8      = (lane & 7) * 8;

    // Q fragments: 64 rows per wave (pre-scaled by QSCALE at projection)
    f16x8 qh[4][2];
    {
        int qr = q0 + w*64 + l15;
        #pragma unroll
        for (int mi = 0; mi < 4; ++mi)
            #pragma unroll
            for (int kk = 0; kk < 2; ++kk) {
                int d0 = kk*32 + g*8;
                qh[mi][kk] = *(const f16x8*)&qf[(rowb + qr + mi*16)*64 + d0];
            }
    }

    const f32x4 zero4 = {0.f, 0.f, 0.f, 0.f};
    f16x8 ones8;
    #pragma unroll
    for (int e = 0; e < 8; ++e) ones8[e] = (f16)1.0f;

    f32x4 O[4][4];
    f32x4 lacc[4];
    #pragma unroll
    for (int mi = 0; mi < 4; ++mi) {
        lacc[mi] = zero4;
        #pragma unroll
        for (int oj = 0; oj < 4; ++oj) O[mi][oj] = zero4;
    }

#define STAGE_KV(bsel, kt_) do { \
        _Pragma("unroll") \
        for (int c = 0; c < 2; ++c) { \
            int lrow = w*16 + c*8; \
            int row = lrow + srow_off; \
            int dsw = sd8 ^ ((row & 7) << 3); \
            size_t kg = (rowb + (kt_)*64 + row)*64 + dsw; \
            size_t vg = ((size_t)bh*HD_ + row)*S_ + (kt_)*64 + dsw; \
            gload_lds16(&kf[kg],  &Kh[bsel][lrow][0]); \
            gload_lds16(&vtf[vg], &Vth[bsel][lrow][0]); \
        } \
    } while (0)

    // prologue: stage tile 0 into buf 0
    STAGE_KV(0, 0);

    const int NT = S_/64;   // 32
    for (int kt = 0; kt < NT; ++kt) {
        const int cur = kt & 1;
        if (kt + 1 < NT) {
            STAGE_KV(cur ^ 1, kt + 1);                    // next tile in flight
            asm volatile("s_waitcnt vmcnt(4)" ::: "memory");  // cur tile landed
        } else {
            asm volatile("s_waitcnt vmcnt(0)" ::: "memory");
        }
        __builtin_amdgcn_s_barrier();   // all waves' cur-tile loads complete

        // ---- S^T = (K Q^T) single-term f16, sa[kvblock][qblock] ----
        // kk=0 uses shared zero4 as C (no per-kt sa zero-init movs)
        f32x4 sa[4][4];
        {
            f16x8 kb[4];
            #pragma unroll
            for (int k4 = 0; k4 < 4; ++k4) {
                int kv = k4*16 + l15;
                int dw = (g*8) ^ ((kv & 7) << 3);
                kb[k4] = *(const f16x8*)&Kh[cur][kv][dw];
            }
            __builtin_amdgcn_s_setprio(1);
            #pragma unroll
            for (int k4 = 0; k4 < 4; ++k4)
                #pragma unroll
                for (int qt = 0; qt < 4; ++qt)
                    sa[k4][qt] = MFMA16(kb[k4], qh[qt][0], zero4);
            __builtin_amdgcn_s_setprio(0);
        }
        {
            f16x8 kb[4];
            #pragma unroll
            for (int k4 = 0; k4 < 4; ++k4) {
                int kv = k4*16 + l15;
                int dw = (32 + g*8) ^ ((kv & 7) << 3);
                kb[k4] = *(const f16x8*)&Kh[cur][kv][dw];
            }
            __builtin_amdgcn_s_setprio(1);
            #pragma unroll
            for (int k4 = 0; k4 < 4; ++k4)
                #pragma unroll
                for (int qt = 0; qt < 4; ++qt)
                    sa[k4][qt] = MFMA16(kb[k4], qh[qt][1], sa[k4][qt]);
            __builtin_amdgcn_s_setprio(0);
        }

        // ---- P = exp2(score); packed b64 P writes (l-sum moved to MFMA) ----
        u16* Pflat = &Ps[0][0];
        #pragma unroll
        for (int qt = 0; qt < 4; ++qt) {
            int qw = w*64 + qt*16 + l15;
            int prow = qw * 64;
            int sw = (qw & 7) << 3;
            #pragma unroll
            for (int k4 = 0; k4 < 4; ++k4) {
                float p0 = exp2f(sa[k4][qt][0]);
                float p1 = exp2f(sa[k4][qt][1]);
                float p2 = exp2f(sa[k4][qt][2]);
                float p3 = exp2f(sa[k4][qt][3]);
                uint2 pk;
                pk.x = pkh(p0, p1);
                pk.y = pkh(p2, p3);
                int kvb = k4*16 + g*4;
                *(uint2*)&Pflat[prow + (kvb ^ sw)] = pk;
            }
        }
        // no barrier: P rows are wave-private (written and read by same wave)

        // ---- PV (f16 single-term) + l-sum via ones-MFMA ----
        #pragma unroll
        for (int k2 = 0; k2 < 2; ++k2) {
            f16x8 pa[4], vb[4];
            #pragma unroll
            for (int mi = 0; mi < 4; ++mi) {
                int q = w*64 + mi*16 + l15;
                int kw = (k2*32 + g*8) ^ ((q & 7) << 3);
                pa[mi] = *(const f16x8*)&Pflat[q*64 + kw];
            }
            #pragma unroll
            for (int oj = 0; oj < 4; ++oj) {
                int hd = oj*16 + l15;
                int kw = (k2*32 + g*8) ^ ((hd & 7) << 3);
                vb[oj] = *(const f16x8*)&Vth[cur][hd][kw];
            }
            __builtin_amdgcn_s_setprio(1);
            #pragma unroll
            for (int mi = 0; mi < 4; ++mi) {
                #pragma unroll
                for (int oj = 0; oj < 4; ++oj)
                    O[mi][oj] = MFMA16(pa[mi], vb[oj], O[mi][oj]);
                lacc[mi] = MFMA16(pa[mi], ones8, lacc[mi]);   // row-sum of P
            }
            __builtin_amdgcn_s_setprio(0);
        }

        __builtin_amdgcn_s_barrier();   // buf[cur] reads done before restage
    }
#undef STAGE_KV

    // ---- normalize + store f16 in-place over own qf rows ----
    // lacc[mi][r] holds l for row q = w*64 + mi*16 + g*4 + r (all cols equal)
    #pragma unroll
    for (int mi = 0; mi < 4; ++mi)
        #pragma unroll
        for (int r = 0; r < 4; ++r) {
            float iv = 1.f / lacc[mi][r];
            int q = q0 + w*64 + mi*16 + g*4 + r;
            #pragma unroll
            for (int oj = 0; oj < 4; ++oj) {
                int hd = oj*16 + l15;
                qf[(rowb + q)*HD_ + hd] = (f16)(O[mi][oj][r] * iv);
            }
        }
}

extern "C" void kernel_launch(void* const* d_in, const int* in_sizes, int n_in,
                              void* d_out, int out_size, void* d_ws, size_t ws_size,
                              hipStream_t stream) {
    const float* query = (const float*)d_in[0];
    const float* key_  = (const float*)d_in[1];
    const float* value = (const float*)d_in[2];
    const float* Wq    = (const float*)d_in[3];
    const float* bq    = (const float*)d_in[4];
    const float* Wk    = (const float*)d_in[5];
    const float* bk    = (const float*)d_in[6];
    const float* Wv    = (const float*)d_in[7];
    const float* bv    = (const float*)d_in[8];
    const float* Wo    = (const float*)d_in[9];
    const float* bo    = (const float*)d_in[10];
    float* out = (float*)d_out;

    char* wsb = (char*)d_ws;
    const size_t SZ_H = (size_t)BH_*S_*64*2;          // 16.78 MB per f16 tensor
    f16* qf   = (f16*)wsb;                            // q -> attn O (in-place)
    f16* kf   = (f16*)(wsb + SZ_H);
    f16* vtf  = (f16*)(wsb + 2*SZ_H);
    f16* in16 = (f16*)(wsb + 3*SZ_H);                 // reused per input
    f16* W16  = (f16*)(wsb + 4*SZ_H);                 // [4][1<<20] f16 = 8 MB
    // total: 4*16.78 + 8 = 75.1 MB (< 100.7 MB proven available in r1)

    dim3 gGemm(512);    // (8192/128)*(1024/128)
    dim3 gAttn(512);    // 64 bh * 8 q-tiles of 256
    dim3 gConv(8192);   // 8.39M/4/256

    conv_w_kernel<<<dim3(1024,4), 256, 0, stream>>>(Wq, Wk, Wv, Wo, W16);
    conv_in_kernel<<<gConv, 256, 0, stream>>>(query, in16);
    gemm_mfma<0><<<gGemm, 256, 0, stream>>>(in16, W16 + ((size_t)0<<20), bq, qf);
    conv_in_kernel<<<gConv, 256, 0, stream>>>(key_, in16);
    gemm_mfma<1><<<gGemm, 256, 0, stream>>>(in16, W16 + ((size_t)1<<20), bk, kf);
    conv_in_kernel<<<gConv, 256, 0, stream>>>(value, in16);
    gemm_mfma<2><<<gGemm, 256, 0, stream>>>(in16, W16 + ((size_t)2<<20), bv, vtf);
    attn_mfma<<<gAttn, 256, 0, stream>>>(kf, vtf, qf);
    gemm_mfma<3><<<gGemm, 256, 0, stream>>>(qf, W16 + ((size_t)3<<20), bo, out);
}